// Round 8
// baseline (658.826 us; speedup 1.0000x reference)
//
#include <hip/hip_runtime.h>
#include <hip/hip_bf16.h>

#define NN 50000
#define EE 1600000
#define DD 512
#define HH 256
#define GG 16
#define BK 96     // bucket capacity (deg ~ Poisson(32), P(>=96) ~ 1e-18)
#define NCH 256   // edge chunks
#define CHSZ 6250 // EE / NCH
#define NCOPY 32  // pooled accumulator copies (atomic-contention fix, r7 post-mortem)
#define PZN (NCOPY * GG * 256 + 1)   // zeroed u32s: pooled copies + ctr

typedef long fp8x8;                                         // 8 fp8 bytes = 2 VGPRs
typedef __attribute__((ext_vector_type(4))) float f32x4;
typedef __attribute__((ext_vector_type(2))) float f32x2;

__device__ __forceinline__ unsigned char f2fp8(float f) {
    return (unsigned char)(__builtin_amdgcn_cvt_pk_fp8_f32(f, f, 0, false) & 0xff);
}
__device__ __forceinline__ unsigned int pk4fp8(float a, float b, float c, float d) {
    unsigned int r = __builtin_amdgcn_cvt_pk_fp8_f32(a, b, 0, false);
    return __builtin_amdgcn_cvt_pk_fp8_f32(c, d, r, true);
}

// ---------------- pass 1 (fused): per-chunk dst histograms (u8x4) + x->fp8 + W->fp8^T ----------------
__global__ __launch_bounds__(256) void k_hist_cvt(const int* __restrict__ ei,
                                                  unsigned int* __restrict__ histg,   // [NCH][12500] u32 = 4 dsts/u32
                                                  const float* __restrict__ x, unsigned char* __restrict__ xb,
                                                  const float* __restrict__ W1, const float* __restrict__ W2,
                                                  const float* __restrict__ W3, unsigned char* __restrict__ W1t,
                                                  unsigned char* __restrict__ W2t, unsigned char* __restrict__ W3t) {
    __shared__ unsigned int hp[6250];   // 25000 u8 counters
    int b = blockIdx.x, t = threadIdx.x;
    if (b < 512) {
        int j = b >> 1, half = b & 1;
        int dlo = half * 25000;         // 25000 % 4 == 0 -> (d&3) preserved in local idx
        for (int i = t; i < 6250; i += 256) hp[i] = 0;
        __syncthreads();
        int base = j * CHSZ;
        for (int k = 0; k < 25; ++k) {
            int o = k * 256 + t;
            if (o < CHSZ) {
                int d = ei[EE + base + o];
                unsigned int ld = (unsigned)(d - dlo);
                if (ld < 25000u) atomicAdd(&hp[ld >> 2], 1u << ((ld & 3) * 8));
            }
        }
        __syncthreads();
        unsigned int* dst = histg + (size_t)j * 12500 + half * 6250;
        for (int i = t; i < 6250; i += 256) dst[i] = hp[i];
    } else if (b < 6762) {
        size_t i0 = ((size_t)(b - 512) * 256 + t) * 16;   // 16 floats per thread
        float4 v0 = *(const float4*)(x + i0);
        float4 v1 = *(const float4*)(x + i0 + 4);
        float4 v2 = *(const float4*)(x + i0 + 8);
        float4 v3 = *(const float4*)(x + i0 + 12);
        uint4 o;
        o.x = pk4fp8(v0.x, v0.y, v0.z, v0.w);
        o.y = pk4fp8(v1.x, v1.y, v1.z, v1.w);
        o.z = pk4fp8(v2.x, v2.y, v2.z, v2.w);
        o.w = pk4fp8(v3.x, v3.y, v3.z, v3.w);
        *(uint4*)(xb + i0) = o;
    } else {
        int u = (b - 6762) * 256 + t;
        if (u < 131072) {
            int k = u >> 8, n = u & 255;
            W1t[(size_t)n * 512 + k] = f2fp8(W1[u]);
        } else if (u < 196608) {
            int q = u - 131072; int k = q >> 8, n = q & 255;
            W2t[(size_t)n * 256 + k] = f2fp8(W2[q]);
        } else {
            int q = u - 196608; int k = q >> 8, n = q & 255;
            W3t[(size_t)n * 256 + k] = f2fp8(W3[q]);
        }
    }
}

// ---------------- pass 2: exclusive scan over chunks (u8 lanes) + cnt/dinv; blocks 391..399 zero pooled copies + ctr ----------------
__global__ __launch_bounds__(256) void k_scan(const unsigned int* __restrict__ histg,
                                              unsigned int* __restrict__ offg,    // [NCH][25000] u32 = 2 dsts/u32 (u16)
                                              int* __restrict__ cnt, float* __restrict__ dinv,
                                              unsigned int* __restrict__ zero0) { // pooled copies..ctr contiguous
    __shared__ unsigned int part[512];
    int t = threadIdx.x, b = blockIdx.x;
    if (b >= 391) {
        int zb = b - 391;                       // 9 zero blocks
        int per = (PZN + 8) / 9;
        int z0 = zb * per, z1 = z0 + per; if (z1 > PZN) z1 = PZN;
        for (int i = z0 + t; i < z1; i += 256) zero0[i] = 0u;
        return;
    }
    const int il = t & 31, g = t >> 5;
    const int g4 = b * 32 + il;          // dst4-group id
    const bool ok = (g4 < 12500);
    unsigned hv[32];
    unsigned s02 = 0, s13 = 0;           // byte0/2 and byte1/3 sums (u16 halves; <=255*32 no carry)
    if (ok) {
        const unsigned* hp = histg + (size_t)(g * 32) * 12500 + g4;
        #pragma unroll
        for (int jj = 0; jj < 32; ++jj) hv[jj] = hp[(size_t)jj * 12500];
        #pragma unroll
        for (int jj = 0; jj < 32; ++jj) { s02 += hv[jj] & 0x00ff00ffu; s13 += (hv[jj] >> 8) & 0x00ff00ffu; }
    }
    part[t * 2] = s02; part[t * 2 + 1] = s13;
    __syncthreads();
    unsigned b02 = 0, b13 = 0;
    #pragma unroll
    for (int g2 = 0; g2 < 7; ++g2)
        if (g2 < g) { b02 += part[(g2 * 32 + il) * 2]; b13 += part[(g2 * 32 + il) * 2 + 1]; }
    if (ok && g == 7) {
        unsigned t02 = b02 + s02, t13 = b13 + s13;
        int4 cv; cv.x = (int)(t02 & 0xffffu); cv.y = (int)(t13 & 0xffffu);
        cv.z = (int)(t02 >> 16);      cv.w = (int)(t13 >> 16);
        *(int4*)(cnt + 4 * g4) = cv;
        float4 dv;
        dv.x = rsqrtf((float)cv.x + 1.0f); dv.y = rsqrtf((float)cv.y + 1.0f);
        dv.z = rsqrtf((float)cv.z + 1.0f); dv.w = rsqrtf((float)cv.w + 1.0f);
        *(float4*)(dinv + 4 * g4) = dv;
    }
    if (ok) {
        unsigned r0 = b02 & 0xffffu, r2 = b02 >> 16, r1 = b13 & 0xffffu, r3 = b13 >> 16;
        #pragma unroll
        for (int jj = 0; jj < 32; ++jj) {
            uint2 wv; wv.x = r0 | (r1 << 16); wv.y = r2 | (r3 << 16);
            *(uint2*)(offg + (size_t)(g * 32 + jj) * 25000 + 2 * g4) = wv;
            unsigned h = hv[jj];
            r0 += h & 0xffu; r1 += (h >> 8) & 0xffu; r2 += (h >> 16) & 0xffu; r3 += h >> 24;
        }
    }
}

// ---------------- pass 3: atomic-free placement, XCD-partitioned (unchanged) ----------------
__global__ __launch_bounds__(256) void k_place(const int* __restrict__ ei,
                                               const unsigned int* __restrict__ offg,
                                               unsigned short* __restrict__ bucket) {
    __shared__ unsigned int cur[3125];
    int b = blockIdx.x, t = threadIdx.x;
    int x8 = b & 7, j = b >> 3;
    int lo = x8 * CHSZ;                 // lo even -> parity(ld)==parity(d)
    for (int i = t; i < 3125; i += 256) cur[i] = 0;
    __syncthreads();
    int base = j * CHSZ;
    for (int k = 0; k < 25; ++k) {
        int o = k * 256 + t;
        if (o < CHSZ) {
            int d = ei[EE + base + o];
            unsigned ld = (unsigned)(d - lo);
            if (ld < 6250u) {
                int s = ei[base + o];
                unsigned old = atomicAdd(&cur[ld >> 1], (ld & 1) ? 65536u : 1u);
                unsigned rank = (ld & 1) ? (old >> 16) : (old & 0xffffu);
                unsigned ov = offg[j * 25000 + (d >> 1)];
                unsigned pos = ((d & 1) ? (ov >> 16) : (ov & 0xffffu)) + rank;
                if (pos < BK) bucket[(size_t)d * BK + pos] = (unsigned short)s;
            }
        }
    }
}

// ---------------- fp8 MFMA GEMM: C = fp8(dinv[row] * (A @ Bt^T)) (round-4 version) ----------------
__global__ __launch_bounds__(256) void k_gemm_fp8(const unsigned char* __restrict__ A,
                                                  const unsigned char* __restrict__ Bt,
                                                  const float* __restrict__ dinv,
                                                  unsigned char* __restrict__ C, int M, int K) {
    __shared__ unsigned char As[2][8192];   // [buf][128 rows][64 B]
    __shared__ unsigned char Bs[2][8192];
    const int tid  = threadIdx.x;
    const int wave = tid >> 6;
    const int lane = tid & 63;
    const int row0 = blockIdx.x * 128;
    const int col0 = blockIdx.y * 128;
    const int wr = wave & 1;
    const int wc = wave >> 1;
    const int l15 = lane & 15;
    const int quad = lane >> 4;

    const int srow = (wave << 4) + (lane >> 2);
    const int gk16 = (((lane & 3) ^ (srow & 3)) << 4);
    int arow1 = row0 + srow;      if (arow1 >= M) arow1 = M - 1;
    int arow2 = row0 + srow + 64; if (arow2 >= M) arow2 = M - 1;
    const int brow1 = col0 + srow;
    const int brow2 = brow1 + 64;

#define STAGE(BUF, KB) do {                                                              \
    const unsigned char* ga1_ = A  + (size_t)arow1 * K + (KB) + gk16;                    \
    const unsigned char* ga2_ = A  + (size_t)arow2 * K + (KB) + gk16;                    \
    const unsigned char* gb1_ = Bt + (size_t)brow1 * K + (KB) + gk16;                    \
    const unsigned char* gb2_ = Bt + (size_t)brow2 * K + (KB) + gk16;                    \
    __builtin_amdgcn_global_load_lds((const __attribute__((address_space(1))) void*)ga1_,\
        (__attribute__((address_space(3))) void*)&As[BUF][wave * 1024], 16, 0, 0);       \
    __builtin_amdgcn_global_load_lds((const __attribute__((address_space(1))) void*)ga2_,\
        (__attribute__((address_space(3))) void*)&As[BUF][4096 + wave * 1024], 16, 0, 0);\
    __builtin_amdgcn_global_load_lds((const __attribute__((address_space(1))) void*)gb1_,\
        (__attribute__((address_space(3))) void*)&Bs[BUF][wave * 1024], 16, 0, 0);       \
    __builtin_amdgcn_global_load_lds((const __attribute__((address_space(1))) void*)gb2_,\
        (__attribute__((address_space(3))) void*)&Bs[BUF][4096 + wave * 1024], 16, 0, 0);\
} while (0)

    f32x4 acc[4][4];
    #pragma unroll
    for (int i = 0; i < 4; ++i)
        #pragma unroll
        for (int j = 0; j < 4; ++j)
            acc[i][j] = (f32x4){0.f, 0.f, 0.f, 0.f};

    const int NT = K >> 6;    // K=512 -> 8, K=256 -> 4
    STAGE(0, 0);
    __syncthreads();

    for (int t = 0; t < NT; ++t) {
        const int cb = t & 1;
        if (t + 1 < NT) STAGE(cb ^ 1, (t + 1) << 6);

        fp8x8 af[2][4], bfr[2][4];
        #pragma unroll
        for (int kk = 0; kk < 2; ++kk) {
            const int csw = (((kk * 2 + (quad >> 1)) ^ (l15 & 3)) << 4) + ((quad & 1) << 3);
            #pragma unroll
            for (int mi = 0; mi < 4; ++mi) {
                af[kk][mi]  = *(const fp8x8*)&As[cb][(wr * 64 + mi * 16 + l15) * 64 + csw];
                bfr[kk][mi] = *(const fp8x8*)&Bs[cb][(wc * 64 + mi * 16 + l15) * 64 + csw];
            }
        }
        #pragma unroll
        for (int kk = 0; kk < 2; ++kk)
            #pragma unroll
            for (int mi = 0; mi < 4; ++mi)
                #pragma unroll
                for (int ni = 0; ni < 4; ++ni)
                    acc[mi][ni] = __builtin_amdgcn_mfma_f32_16x16x32_fp8_fp8(af[kk][mi], bfr[kk][ni], acc[mi][ni], 0, 0, 0);

        __syncthreads();
    }
#undef STAGE

    #pragma unroll
    for (int mi = 0; mi < 4; ++mi) {
        #pragma unroll
        for (int r = 0; r < 4; ++r) {
            int grow = row0 + wr * 64 + mi * 16 + quad * 4 + r;
            if (grow < M) {
                float ds = dinv[grow];
                #pragma unroll
                for (int ni = 0; ni < 4; ++ni) {
                    int gcol = col0 + wc * 64 + ni * 16 + l15;
                    C[(size_t)grow * 256 + gcol] = f2fp8(ds * acc[mi][ni][r]);
                }
            }
        }
    }
}

// ---------------- aggregation over fp8 rows; fp8 h output ----------------
__global__ __launch_bounds__(256) void k_agg(const unsigned int* __restrict__ m,   // [NN][64] dwords
                                             const float* __restrict__ bias,
                                             const float* __restrict__ dinv, const int* __restrict__ cnt,
                                             const unsigned short* __restrict__ bucket,
                                             unsigned int* __restrict__ outb,      // [NN][64] dwords fp8
                                             int do_relu) {
    int lane = threadIdx.x & 63;
    int node = blockIdx.x * 4 + (threadIdx.x >> 6);
    if (node >= NN) return;
    const unsigned int* mrow = m + lane;
    unsigned int v = mrow[(size_t)node * 64];
    f32x2 lo = __builtin_amdgcn_cvt_pk_f32_fp8(v, false);
    f32x2 hi = __builtin_amdgcn_cvt_pk_f32_fp8(v, true);
    float4 acc = make_float4(lo.x, lo.y, hi.x, hi.y);
    int n = cnt[node]; if (n > BK) n = BK;
    const unsigned short* cs = bucket + (size_t)node * BK;
    int p = 0;
    for (; p + 16 <= n; p += 16) {
        uint4 iv0 = *(const uint4*)(cs + p);        // 8 u16 indices
        uint4 iv1 = *(const uint4*)(cs + p + 8);
        unsigned int u0 = mrow[(size_t)(iv0.x & 0xffffu) * 64];
        unsigned int u1 = mrow[(size_t)(iv0.x >> 16)    * 64];
        unsigned int u2 = mrow[(size_t)(iv0.y & 0xffffu) * 64];
        unsigned int u3 = mrow[(size_t)(iv0.y >> 16)    * 64];
        unsigned int u4 = mrow[(size_t)(iv0.z & 0xffffu) * 64];
        unsigned int u5 = mrow[(size_t)(iv0.z >> 16)    * 64];
        unsigned int u6 = mrow[(size_t)(iv0.w & 0xffffu) * 64];
        unsigned int u7 = mrow[(size_t)(iv0.w >> 16)    * 64];
        unsigned int u8 = mrow[(size_t)(iv1.x & 0xffffu) * 64];
        unsigned int u9 = mrow[(size_t)(iv1.x >> 16)    * 64];
        unsigned int ua = mrow[(size_t)(iv1.y & 0xffffu) * 64];
        unsigned int ub = mrow[(size_t)(iv1.y >> 16)    * 64];
        unsigned int uc = mrow[(size_t)(iv1.z & 0xffffu) * 64];
        unsigned int ud = mrow[(size_t)(iv1.z >> 16)    * 64];
        unsigned int ue = mrow[(size_t)(iv1.w & 0xffffu) * 64];
        unsigned int uf = mrow[(size_t)(iv1.w >> 16)    * 64];
        f32x2 a0 = __builtin_amdgcn_cvt_pk_f32_fp8(u0, false), b0 = __builtin_amdgcn_cvt_pk_f32_fp8(u0, true);
        f32x2 a1 = __builtin_amdgcn_cvt_pk_f32_fp8(u1, false), b1 = __builtin_amdgcn_cvt_pk_f32_fp8(u1, true);
        f32x2 a2 = __builtin_amdgcn_cvt_pk_f32_fp8(u2, false), b2 = __builtin_amdgcn_cvt_pk_f32_fp8(u2, true);
        f32x2 a3 = __builtin_amdgcn_cvt_pk_f32_fp8(u3, false), b3 = __builtin_amdgcn_cvt_pk_f32_fp8(u3, true);
        f32x2 a4 = __builtin_amdgcn_cvt_pk_f32_fp8(u4, false), b4 = __builtin_amdgcn_cvt_pk_f32_fp8(u4, true);
        f32x2 a5 = __builtin_amdgcn_cvt_pk_f32_fp8(u5, false), b5 = __builtin_amdgcn_cvt_pk_f32_fp8(u5, true);
        f32x2 a6 = __builtin_amdgcn_cvt_pk_f32_fp8(u6, false), b6 = __builtin_amdgcn_cvt_pk_f32_fp8(u6, true);
        f32x2 a7 = __builtin_amdgcn_cvt_pk_f32_fp8(u7, false), b7 = __builtin_amdgcn_cvt_pk_f32_fp8(u7, true);
        f32x2 a8 = __builtin_amdgcn_cvt_pk_f32_fp8(u8, false), b8 = __builtin_amdgcn_cvt_pk_f32_fp8(u8, true);
        f32x2 a9 = __builtin_amdgcn_cvt_pk_f32_fp8(u9, false), b9 = __builtin_amdgcn_cvt_pk_f32_fp8(u9, true);
        f32x2 aa = __builtin_amdgcn_cvt_pk_f32_fp8(ua, false), ba = __builtin_amdgcn_cvt_pk_f32_fp8(ua, true);
        f32x2 ab = __builtin_amdgcn_cvt_pk_f32_fp8(ub, false), bb2 = __builtin_amdgcn_cvt_pk_f32_fp8(ub, true);
        f32x2 ac = __builtin_amdgcn_cvt_pk_f32_fp8(uc, false), bc = __builtin_amdgcn_cvt_pk_f32_fp8(uc, true);
        f32x2 ad = __builtin_amdgcn_cvt_pk_f32_fp8(ud, false), bd = __builtin_amdgcn_cvt_pk_f32_fp8(ud, true);
        f32x2 ae = __builtin_amdgcn_cvt_pk_f32_fp8(ue, false), be = __builtin_amdgcn_cvt_pk_f32_fp8(ue, true);
        f32x2 af2 = __builtin_amdgcn_cvt_pk_f32_fp8(uf, false), bf2 = __builtin_amdgcn_cvt_pk_f32_fp8(uf, true);
        acc.x += (((a0.x + a1.x) + (a2.x + a3.x)) + ((a4.x + a5.x) + (a6.x + a7.x)))
               + (((a8.x + a9.x) + (aa.x + ab.x)) + ((ac.x + ad.x) + (ae.x + af2.x)));
        acc.y += (((a0.y + a1.y) + (a2.y + a3.y)) + ((a4.y + a5.y) + (a6.y + a7.y)))
               + (((a8.y + a9.y) + (aa.y + ab.y)) + ((ac.y + ad.y) + (ae.y + af2.y)));
        acc.z += (((b0.x + b1.x) + (b2.x + b3.x)) + ((b4.x + b5.x) + (b6.x + b7.x)))
               + (((b8.x + b9.x) + (ba.x + bb2.x)) + ((bc.x + bd.x) + (be.x + bf2.x)));
        acc.w += (((b0.y + b1.y) + (b2.y + b3.y)) + ((b4.y + b5.y) + (b6.y + b7.y)))
               + (((b8.y + b9.y) + (ba.y + bb2.y)) + ((bc.y + bd.y) + (be.y + bf2.y)));
    }
    for (; p + 8 <= n; p += 8) {
        uint4 iv0 = *(const uint4*)(cs + p);
        unsigned int u0 = mrow[(size_t)(iv0.x & 0xffffu) * 64];
        unsigned int u1 = mrow[(size_t)(iv0.x >> 16)    * 64];
        unsigned int u2 = mrow[(size_t)(iv0.y & 0xffffu) * 64];
        unsigned int u3 = mrow[(size_t)(iv0.y >> 16)    * 64];
        unsigned int u4 = mrow[(size_t)(iv0.z & 0xffffu) * 64];
        unsigned int u5 = mrow[(size_t)(iv0.z >> 16)    * 64];
        unsigned int u6 = mrow[(size_t)(iv0.w & 0xffffu) * 64];
        unsigned int u7 = mrow[(size_t)(iv0.w >> 16)    * 64];
        f32x2 a0 = __builtin_amdgcn_cvt_pk_f32_fp8(u0, false), b0 = __builtin_amdgcn_cvt_pk_f32_fp8(u0, true);
        f32x2 a1 = __builtin_amdgcn_cvt_pk_f32_fp8(u1, false), b1 = __builtin_amdgcn_cvt_pk_f32_fp8(u1, true);
        f32x2 a2 = __builtin_amdgcn_cvt_pk_f32_fp8(u2, false), b2 = __builtin_amdgcn_cvt_pk_f32_fp8(u2, true);
        f32x2 a3 = __builtin_amdgcn_cvt_pk_f32_fp8(u3, false), b3 = __builtin_amdgcn_cvt_pk_f32_fp8(u3, true);
        f32x2 a4 = __builtin_amdgcn_cvt_pk_f32_fp8(u4, false), b4 = __builtin_amdgcn_cvt_pk_f32_fp8(u4, true);
        f32x2 a5 = __builtin_amdgcn_cvt_pk_f32_fp8(u5, false), b5 = __builtin_amdgcn_cvt_pk_f32_fp8(u5, true);
        f32x2 a6 = __builtin_amdgcn_cvt_pk_f32_fp8(u6, false), b6 = __builtin_amdgcn_cvt_pk_f32_fp8(u6, true);
        f32x2 a7 = __builtin_amdgcn_cvt_pk_f32_fp8(u7, false), b7 = __builtin_amdgcn_cvt_pk_f32_fp8(u7, true);
        acc.x += ((a0.x + a1.x) + (a2.x + a3.x)) + ((a4.x + a5.x) + (a6.x + a7.x));
        acc.y += ((a0.y + a1.y) + (a2.y + a3.y)) + ((a4.y + a5.y) + (a6.y + a7.y));
        acc.z += ((b0.x + b1.x) + (b2.x + b3.x)) + ((b4.x + b5.x) + (b6.x + b7.x));
        acc.w += ((b0.y + b1.y) + (b2.y + b3.y)) + ((b4.y + b5.y) + (b6.y + b7.y));
    }
    for (; p < n; ++p) {
        int s = cs[p];
        unsigned int u = mrow[(size_t)s * 64];
        f32x2 a = __builtin_amdgcn_cvt_pk_f32_fp8(u, false);
        f32x2 b = __builtin_amdgcn_cvt_pk_f32_fp8(u, true);
        acc.x += a.x; acc.y += a.y; acc.z += b.x; acc.w += b.y;
    }
    float di = dinv[node];
    const float4 bb = *(const float4*)(bias + lane * 4);
    acc.x = acc.x * di + bb.x; acc.y = acc.y * di + bb.y;
    acc.z = acc.z * di + bb.z; acc.w = acc.w * di + bb.w;
    if (do_relu) {
        acc.x = fmaxf(acc.x, 0.f); acc.y = fmaxf(acc.y, 0.f);
        acc.z = fmaxf(acc.z, 0.f); acc.w = fmaxf(acc.w, 0.f);
    }
    outb[(size_t)node * 64 + lane] = pk4fp8(acc.x, acc.y, acc.z, acc.w);
}

// ---------------- pooling + head: 2000 blocks, 32-copy accumulators (contention fix), last-block head ----------------
// r5: 256 blocks = latency-bound (60us, 6% occ). r7: 2000 blocks + single pooled = atomic-contention
// bound (160us, ~1M device atomics on 16KB). Now: block b atomics into copy (b&31) -> 32x less
// per-address contention; head sums the 32 copies (131K loads, trivial).
__global__ __launch_bounds__(256) void k_poolhead(const unsigned int* __restrict__ h,  // [NN][64] dwords
                                                  const int* __restrict__ batch,
                                                  float* __restrict__ pooled,          // [NCOPY][GG*256]
                                                  unsigned int* __restrict__ ctr,
                                                  const float* __restrict__ Wf, const float* __restrict__ bf,
                                                  const float* __restrict__ Wp, const float* __restrict__ bp,
                                                  float* __restrict__ out) {
    __shared__ float pl[GG * 256];
    __shared__ float z[GG][64];
    __shared__ unsigned int ub[GG];
    __shared__ float cl[GG];
    __shared__ unsigned int lastdone;
    int t = threadIdx.x;
    for (int i = t; i < GG * 256; i += 256) pl[i] = 0.f;
    __syncthreads();
    int sub = t >> 6;
    int fd = t & 63;              // feature dword
    int i0 = blockIdx.x * 25;     // grid 2000: exact cover of 50000
    int i1 = i0 + 25;
    int gcur = -1;
    float a0 = 0.f, a1 = 0.f, a2 = 0.f, a3 = 0.f;
    for (int i = i0 + sub; i < i1; i += 4) {
        int g = batch[i];
        if (g != gcur) {
            if (gcur >= 0) {
                atomicAdd(&pl[gcur * 256 + fd * 4 + 0], a0);
                atomicAdd(&pl[gcur * 256 + fd * 4 + 1], a1);
                atomicAdd(&pl[gcur * 256 + fd * 4 + 2], a2);
                atomicAdd(&pl[gcur * 256 + fd * 4 + 3], a3);
            }
            gcur = g; a0 = a1 = a2 = a3 = 0.f;
        }
        unsigned int u = h[(size_t)i * 64 + fd];
        f32x2 lo = __builtin_amdgcn_cvt_pk_f32_fp8(u, false);
        f32x2 hi = __builtin_amdgcn_cvt_pk_f32_fp8(u, true);
        a0 += lo.x; a1 += lo.y; a2 += hi.x; a3 += hi.y;
    }
    if (gcur >= 0) {
        atomicAdd(&pl[gcur * 256 + fd * 4 + 0], a0);
        atomicAdd(&pl[gcur * 256 + fd * 4 + 1], a1);
        atomicAdd(&pl[gcur * 256 + fd * 4 + 2], a2);
        atomicAdd(&pl[gcur * 256 + fd * 4 + 3], a3);
    }
    __syncthreads();
    float* myp = pooled + (size_t)(blockIdx.x & (NCOPY - 1)) * (GG * 256);
    for (int i = t; i < GG * 256; i += 256)
        if (pl[i] != 0.f) atomicAdd(&myp[i], pl[i]);

    // ---- last-block head ----
    __syncthreads();
    __threadfence();
    if (t == 0) lastdone = (atomicAdd(ctr, 1u) == gridDim.x - 1) ? 1u : 0u;
    __syncthreads();
    if (!lastdone) return;
    __threadfence();
    for (int i = t; i < GG * 256; i += 256) {
        float s = 0.f;
        #pragma unroll 4
        for (int c = 0; c < NCOPY; ++c)
            s += __hip_atomic_load(&pooled[(size_t)c * (GG * 256) + i],
                                   __ATOMIC_RELAXED, __HIP_MEMORY_SCOPE_AGENT);
        pl[i] = s;
    }
    if (t < GG) {
        // upper_bound(batch, t): first index with batch[idx] > t (batch sorted)
        int lo2 = 0, hi2 = NN;
        while (lo2 < hi2) { int mid = (lo2 + hi2) >> 1; if (batch[mid] <= t) lo2 = mid + 1; else hi2 = mid; }
        ub[t] = (unsigned)lo2;
    }
    __syncthreads();
    if (t < GG) cl[t] = (float)(ub[t] - (t ? ub[t - 1] : 0u));
    __syncthreads();
    for (int idx = t; idx < GG * 64; idx += 256) {
        int g = idx >> 6, j = idx & 63;
        float inv = 1.f / fmaxf(cl[g], 1.f);
        float acc = 0.f;
        for (int k = 0; k < 256; ++k) acc += pl[g * 256 + k] * Wf[k * 64 + j];
        z[g][j] = acc * inv + bf[j];
    }
    __syncthreads();
    if (t < GG) {
        float o = 0.f;
        for (int j2 = 0; j2 < 64; ++j2) o += z[t][j2] * Wp[j2];
        o += bp[0];
        out[t] = 1.f / (1.f + expf(-o));
    }
}

extern "C" void kernel_launch(void* const* d_in, const int* in_sizes, int n_in,
                              void* d_out, int out_size, void* d_ws, size_t ws_size,
                              hipStream_t stream) {
    const float* x   = (const float*)d_in[0];
    const int*   ei  = (const int*)d_in[1];
    const int*   bat = (const int*)d_in[2];
    const float* W1  = (const float*)d_in[3];
    const float* b1  = (const float*)d_in[4];
    const float* W2  = (const float*)d_in[5];
    const float* b2  = (const float*)d_in[6];
    const float* W3  = (const float*)d_in[7];
    const float* b3  = (const float*)d_in[8];
    const float* Wf  = (const float*)d_in[9];
    const float* bf  = (const float*)d_in[10];
    const float* Wp  = (const float*)d_in[11];
    const float* bp  = (const float*)d_in[12];
    float* out = (float*)d_out;

    char* w = (char*)d_ws;
    unsigned char* xb  = (unsigned char*)w;  w += (size_t)NN * DD;         // fp8 x, 25.6 MB
    unsigned char* mb  = (unsigned char*)w;  w += (size_t)NN * HH;         // fp8 prescaled gemm out
    unsigned char* hb  = (unsigned char*)w;  w += (size_t)NCH * 25000 * 4; // histg (12.8 used), then fp8 h
    unsigned char* hb2 = (unsigned char*)w;  w += (size_t)NCH * 25000 * 4; // offg, then fp8 h
    unsigned char* W1t = (unsigned char*)w;  w += (size_t)DD * HH;
    unsigned char* W2t = (unsigned char*)w;  w += (size_t)HH * HH;
    unsigned char* W3t = (unsigned char*)w;  w += (size_t)HH * HH;
    float* dinv   = (float*)w;               w += (size_t)NN * 4;
    int*   cnt    = (int*)w;                 w += (size_t)NN * 4;
    unsigned short* bucket = (unsigned short*)w; w += (size_t)NN * BK * 2; // 9.6 MB
    float* pooled = (float*)w;               w += (size_t)NCOPY * GG * HH * 4; // 512 KB, 32 copies
    unsigned int* ctr = (unsigned int*)w;    w += 4;

    unsigned int* histg = (unsigned int*)hb;
    unsigned int* offg  = (unsigned int*)hb2;

    // build: fused u8-hist + converts | scan (blks 391..399 zero pooled copies + ctr) | place
    k_hist_cvt<<<7786, 256, 0, stream>>>(ei, histg, x, xb, W1, W2, W3, W1t, W2t, W3t);
    k_scan<<<400, 256, 0, stream>>>(histg, offg, cnt, dinv, (unsigned int*)pooled);
    k_place<<<2048, 256, 0, stream>>>(ei, offg, bucket);

    dim3 gg((NN + 127) / 128, 2);
    // layer 1
    k_gemm_fp8<<<gg, 256, 0, stream>>>(xb, W1t, dinv, mb, NN, DD);
    k_agg<<<(NN + 3) / 4, 256, 0, stream>>>((const unsigned int*)mb, b1, dinv, cnt, bucket,
                                            (unsigned int*)hb, 1);
    // layer 2
    k_gemm_fp8<<<gg, 256, 0, stream>>>(hb, W2t, dinv, mb, NN, HH);
    k_agg<<<(NN + 3) / 4, 256, 0, stream>>>((const unsigned int*)mb, b2, dinv, cnt, bucket,
                                            (unsigned int*)hb2, 1);
    // layer 3
    k_gemm_fp8<<<gg, 256, 0, stream>>>(hb2, W3t, dinv, mb, NN, HH);
    k_agg<<<(NN + 3) / 4, 256, 0, stream>>>((const unsigned int*)mb, b3, dinv, cnt, bucket,
                                            (unsigned int*)hb, 0);

    k_poolhead<<<2000, 256, 0, stream>>>((const unsigned int*)hb, bat, pooled, ctr,
                                         Wf, bf, Wp, bp, out);
}

// Round 9
// 492.162 us; speedup vs baseline: 1.3386x; 1.3386x over previous
//
#include <hip/hip_runtime.h>
#include <hip/hip_bf16.h>

#define NN 50000
#define EE 1600000
#define DD 512
#define HH 256
#define GG 16
#define BK 96     // bucket capacity (deg ~ Poisson(32), P(>=96) ~ 1e-18)
#define NCH 256   // edge chunks
#define CHSZ 6250 // EE / NCH
#define PCH 64    // pooling chunks per graph (grid 16*64, no atomics)

typedef long fp8x8;                                         // 8 fp8 bytes = 2 VGPRs
typedef __attribute__((ext_vector_type(4))) float f32x4;
typedef __attribute__((ext_vector_type(2))) float f32x2;

__device__ __forceinline__ unsigned char f2fp8(float f) {
    return (unsigned char)(__builtin_amdgcn_cvt_pk_fp8_f32(f, f, 0, false) & 0xff);
}
__device__ __forceinline__ unsigned int pk4fp8(float a, float b, float c, float d) {
    unsigned int r = __builtin_amdgcn_cvt_pk_fp8_f32(a, b, 0, false);
    return __builtin_amdgcn_cvt_pk_fp8_f32(c, d, r, true);
}

// ---------------- pass 1 (fused): per-chunk dst histograms (u8x4) + x->fp8 + W->fp8^T ----------------
__global__ __launch_bounds__(256) void k_hist_cvt(const int* __restrict__ ei,
                                                  unsigned int* __restrict__ histg,   // [NCH][12500] u32 = 4 dsts/u32
                                                  const float* __restrict__ x, unsigned char* __restrict__ xb,
                                                  const float* __restrict__ W1, const float* __restrict__ W2,
                                                  const float* __restrict__ W3, unsigned char* __restrict__ W1t,
                                                  unsigned char* __restrict__ W2t, unsigned char* __restrict__ W3t) {
    __shared__ unsigned int hp[6250];   // 25000 u8 counters
    int b = blockIdx.x, t = threadIdx.x;
    if (b < 512) {
        int j = b >> 1, half = b & 1;
        int dlo = half * 25000;         // 25000 % 4 == 0 -> (d&3) preserved in local idx
        for (int i = t; i < 6250; i += 256) hp[i] = 0;
        __syncthreads();
        int base = j * CHSZ;
        for (int k = 0; k < 25; ++k) {
            int o = k * 256 + t;
            if (o < CHSZ) {
                int d = ei[EE + base + o];
                unsigned int ld = (unsigned)(d - dlo);
                if (ld < 25000u) atomicAdd(&hp[ld >> 2], 1u << ((ld & 3) * 8));
            }
        }
        __syncthreads();
        unsigned int* dst = histg + (size_t)j * 12500 + half * 6250;
        for (int i = t; i < 6250; i += 256) dst[i] = hp[i];
    } else if (b < 6762) {
        size_t i0 = ((size_t)(b - 512) * 256 + t) * 16;   // 16 floats per thread
        float4 v0 = *(const float4*)(x + i0);
        float4 v1 = *(const float4*)(x + i0 + 4);
        float4 v2 = *(const float4*)(x + i0 + 8);
        float4 v3 = *(const float4*)(x + i0 + 12);
        uint4 o;
        o.x = pk4fp8(v0.x, v0.y, v0.z, v0.w);
        o.y = pk4fp8(v1.x, v1.y, v1.z, v1.w);
        o.z = pk4fp8(v2.x, v2.y, v2.z, v2.w);
        o.w = pk4fp8(v3.x, v3.y, v3.z, v3.w);
        *(uint4*)(xb + i0) = o;
    } else {
        int u = (b - 6762) * 256 + t;
        if (u < 131072) {
            int k = u >> 8, n = u & 255;
            W1t[(size_t)n * 512 + k] = f2fp8(W1[u]);
        } else if (u < 196608) {
            int q = u - 131072; int k = q >> 8, n = q & 255;
            W2t[(size_t)n * 256 + k] = f2fp8(W2[q]);
        } else {
            int q = u - 196608; int k = q >> 8, n = q & 255;
            W3t[(size_t)n * 256 + k] = f2fp8(W3[q]);
        }
    }
}

// ---------------- pass 2: exclusive scan over chunks (u8 lanes) + cnt/dinv ----------------
__global__ __launch_bounds__(256) void k_scan(const unsigned int* __restrict__ histg,
                                              unsigned int* __restrict__ offg,    // [NCH][25000] u32 = 2 dsts/u32 (u16)
                                              int* __restrict__ cnt, float* __restrict__ dinv) {
    __shared__ unsigned int part[512];
    int t = threadIdx.x, b = blockIdx.x;
    const int il = t & 31, g = t >> 5;
    const int g4 = b * 32 + il;          // dst4-group id
    const bool ok = (g4 < 12500);
    unsigned hv[32];
    unsigned s02 = 0, s13 = 0;           // byte0/2 and byte1/3 sums (u16 halves; <=255*32 no carry)
    if (ok) {
        const unsigned* hp = histg + (size_t)(g * 32) * 12500 + g4;
        #pragma unroll
        for (int jj = 0; jj < 32; ++jj) hv[jj] = hp[(size_t)jj * 12500];
        #pragma unroll
        for (int jj = 0; jj < 32; ++jj) { s02 += hv[jj] & 0x00ff00ffu; s13 += (hv[jj] >> 8) & 0x00ff00ffu; }
    }
    part[t * 2] = s02; part[t * 2 + 1] = s13;
    __syncthreads();
    unsigned b02 = 0, b13 = 0;
    #pragma unroll
    for (int g2 = 0; g2 < 7; ++g2)
        if (g2 < g) { b02 += part[(g2 * 32 + il) * 2]; b13 += part[(g2 * 32 + il) * 2 + 1]; }
    if (ok && g == 7) {
        unsigned t02 = b02 + s02, t13 = b13 + s13;
        int4 cv; cv.x = (int)(t02 & 0xffffu); cv.y = (int)(t13 & 0xffffu);
        cv.z = (int)(t02 >> 16);      cv.w = (int)(t13 >> 16);
        *(int4*)(cnt + 4 * g4) = cv;
        float4 dv;
        dv.x = rsqrtf((float)cv.x + 1.0f); dv.y = rsqrtf((float)cv.y + 1.0f);
        dv.z = rsqrtf((float)cv.z + 1.0f); dv.w = rsqrtf((float)cv.w + 1.0f);
        *(float4*)(dinv + 4 * g4) = dv;
    }
    if (ok) {
        unsigned r0 = b02 & 0xffffu, r2 = b02 >> 16, r1 = b13 & 0xffffu, r3 = b13 >> 16;
        #pragma unroll
        for (int jj = 0; jj < 32; ++jj) {
            uint2 wv; wv.x = r0 | (r1 << 16); wv.y = r2 | (r3 << 16);
            *(uint2*)(offg + (size_t)(g * 32 + jj) * 25000 + 2 * g4) = wv;
            unsigned h = hv[jj];
            r0 += h & 0xffu; r1 += (h >> 8) & 0xffu; r2 += (h >> 16) & 0xffu; r3 += h >> 24;
        }
    }
}

// ---------------- pass 3: atomic-free placement, XCD-partitioned (unchanged) ----------------
__global__ __launch_bounds__(256) void k_place(const int* __restrict__ ei,
                                               const unsigned int* __restrict__ offg,
                                               unsigned short* __restrict__ bucket) {
    __shared__ unsigned int cur[3125];
    int b = blockIdx.x, t = threadIdx.x;
    int x8 = b & 7, j = b >> 3;
    int lo = x8 * CHSZ;                 // lo even -> parity(ld)==parity(d)
    for (int i = t; i < 3125; i += 256) cur[i] = 0;
    __syncthreads();
    int base = j * CHSZ;
    for (int k = 0; k < 25; ++k) {
        int o = k * 256 + t;
        if (o < CHSZ) {
            int d = ei[EE + base + o];
            unsigned ld = (unsigned)(d - lo);
            if (ld < 6250u) {
                int s = ei[base + o];
                unsigned old = atomicAdd(&cur[ld >> 1], (ld & 1) ? 65536u : 1u);
                unsigned rank = (ld & 1) ? (old >> 16) : (old & 0xffffu);
                unsigned ov = offg[j * 25000 + (d >> 1)];
                unsigned pos = ((d & 1) ? (ov >> 16) : (ov & 0xffffu)) + rank;
                if (pos < BK) bucket[(size_t)d * BK + pos] = (unsigned short)s;
            }
        }
    }
}

// ---------------- fp8 MFMA GEMM: C = fp8(dinv[row] * (A @ Bt^T)) (round-4 version) ----------------
__global__ __launch_bounds__(256) void k_gemm_fp8(const unsigned char* __restrict__ A,
                                                  const unsigned char* __restrict__ Bt,
                                                  const float* __restrict__ dinv,
                                                  unsigned char* __restrict__ C, int M, int K) {
    __shared__ unsigned char As[2][8192];   // [buf][128 rows][64 B]
    __shared__ unsigned char Bs[2][8192];
    const int tid  = threadIdx.x;
    const int wave = tid >> 6;
    const int lane = tid & 63;
    const int row0 = blockIdx.x * 128;
    const int col0 = blockIdx.y * 128;
    const int wr = wave & 1;
    const int wc = wave >> 1;
    const int l15 = lane & 15;
    const int quad = lane >> 4;

    const int srow = (wave << 4) + (lane >> 2);
    const int gk16 = (((lane & 3) ^ (srow & 3)) << 4);
    int arow1 = row0 + srow;      if (arow1 >= M) arow1 = M - 1;
    int arow2 = row0 + srow + 64; if (arow2 >= M) arow2 = M - 1;
    const int brow1 = col0 + srow;
    const int brow2 = brow1 + 64;

#define STAGE(BUF, KB) do {                                                              \
    const unsigned char* ga1_ = A  + (size_t)arow1 * K + (KB) + gk16;                    \
    const unsigned char* ga2_ = A  + (size_t)arow2 * K + (KB) + gk16;                    \
    const unsigned char* gb1_ = Bt + (size_t)brow1 * K + (KB) + gk16;                    \
    const unsigned char* gb2_ = Bt + (size_t)brow2 * K + (KB) + gk16;                    \
    __builtin_amdgcn_global_load_lds((const __attribute__((address_space(1))) void*)ga1_,\
        (__attribute__((address_space(3))) void*)&As[BUF][wave * 1024], 16, 0, 0);       \
    __builtin_amdgcn_global_load_lds((const __attribute__((address_space(1))) void*)ga2_,\
        (__attribute__((address_space(3))) void*)&As[BUF][4096 + wave * 1024], 16, 0, 0);\
    __builtin_amdgcn_global_load_lds((const __attribute__((address_space(1))) void*)gb1_,\
        (__attribute__((address_space(3))) void*)&Bs[BUF][wave * 1024], 16, 0, 0);       \
    __builtin_amdgcn_global_load_lds((const __attribute__((address_space(1))) void*)gb2_,\
        (__attribute__((address_space(3))) void*)&Bs[BUF][4096 + wave * 1024], 16, 0, 0);\
} while (0)

    f32x4 acc[4][4];
    #pragma unroll
    for (int i = 0; i < 4; ++i)
        #pragma unroll
        for (int j = 0; j < 4; ++j)
            acc[i][j] = (f32x4){0.f, 0.f, 0.f, 0.f};

    const int NT = K >> 6;    // K=512 -> 8, K=256 -> 4
    STAGE(0, 0);
    __syncthreads();

    for (int t = 0; t < NT; ++t) {
        const int cb = t & 1;
        if (t + 1 < NT) STAGE(cb ^ 1, (t + 1) << 6);

        fp8x8 af[2][4], bfr[2][4];
        #pragma unroll
        for (int kk = 0; kk < 2; ++kk) {
            const int csw = (((kk * 2 + (quad >> 1)) ^ (l15 & 3)) << 4) + ((quad & 1) << 3);
            #pragma unroll
            for (int mi = 0; mi < 4; ++mi) {
                af[kk][mi]  = *(const fp8x8*)&As[cb][(wr * 64 + mi * 16 + l15) * 64 + csw];
                bfr[kk][mi] = *(const fp8x8*)&Bs[cb][(wc * 64 + mi * 16 + l15) * 64 + csw];
            }
        }
        #pragma unroll
        for (int kk = 0; kk < 2; ++kk)
            #pragma unroll
            for (int mi = 0; mi < 4; ++mi)
                #pragma unroll
                for (int ni = 0; ni < 4; ++ni)
                    acc[mi][ni] = __builtin_amdgcn_mfma_f32_16x16x32_fp8_fp8(af[kk][mi], bfr[kk][ni], acc[mi][ni], 0, 0, 0);

        __syncthreads();
    }
#undef STAGE

    #pragma unroll
    for (int mi = 0; mi < 4; ++mi) {
        #pragma unroll
        for (int r = 0; r < 4; ++r) {
            int grow = row0 + wr * 64 + mi * 16 + quad * 4 + r;
            if (grow < M) {
                float ds = dinv[grow];
                #pragma unroll
                for (int ni = 0; ni < 4; ++ni) {
                    int gcol = col0 + wc * 64 + ni * 16 + l15;
                    C[(size_t)grow * 256 + gcol] = f2fp8(ds * acc[mi][ni][r]);
                }
            }
        }
    }
}

// ---------------- aggregation over fp8 rows; fp8 h output ----------------
__global__ __launch_bounds__(256) void k_agg(const unsigned int* __restrict__ m,   // [NN][64] dwords
                                             const float* __restrict__ bias,
                                             const float* __restrict__ dinv, const int* __restrict__ cnt,
                                             const unsigned short* __restrict__ bucket,
                                             unsigned int* __restrict__ outb,      // [NN][64] dwords fp8
                                             int do_relu) {
    int lane = threadIdx.x & 63;
    int node = blockIdx.x * 4 + (threadIdx.x >> 6);
    if (node >= NN) return;
    const unsigned int* mrow = m + lane;
    unsigned int v = mrow[(size_t)node * 64];
    f32x2 lo = __builtin_amdgcn_cvt_pk_f32_fp8(v, false);
    f32x2 hi = __builtin_amdgcn_cvt_pk_f32_fp8(v, true);
    float4 acc = make_float4(lo.x, lo.y, hi.x, hi.y);
    int n = cnt[node]; if (n > BK) n = BK;
    const unsigned short* cs = bucket + (size_t)node * BK;
    int p = 0;
    for (; p + 16 <= n; p += 16) {
        uint4 iv0 = *(const uint4*)(cs + p);        // 8 u16 indices
        uint4 iv1 = *(const uint4*)(cs + p + 8);
        unsigned int u0 = mrow[(size_t)(iv0.x & 0xffffu) * 64];
        unsigned int u1 = mrow[(size_t)(iv0.x >> 16)    * 64];
        unsigned int u2 = mrow[(size_t)(iv0.y & 0xffffu) * 64];
        unsigned int u3 = mrow[(size_t)(iv0.y >> 16)    * 64];
        unsigned int u4 = mrow[(size_t)(iv0.z & 0xffffu) * 64];
        unsigned int u5 = mrow[(size_t)(iv0.z >> 16)    * 64];
        unsigned int u6 = mrow[(size_t)(iv0.w & 0xffffu) * 64];
        unsigned int u7 = mrow[(size_t)(iv0.w >> 16)    * 64];
        unsigned int u8 = mrow[(size_t)(iv1.x & 0xffffu) * 64];
        unsigned int u9 = mrow[(size_t)(iv1.x >> 16)    * 64];
        unsigned int ua = mrow[(size_t)(iv1.y & 0xffffu) * 64];
        unsigned int ub = mrow[(size_t)(iv1.y >> 16)    * 64];
        unsigned int uc = mrow[(size_t)(iv1.z & 0xffffu) * 64];
        unsigned int ud = mrow[(size_t)(iv1.z >> 16)    * 64];
        unsigned int ue = mrow[(size_t)(iv1.w & 0xffffu) * 64];
        unsigned int uf = mrow[(size_t)(iv1.w >> 16)    * 64];
        f32x2 a0 = __builtin_amdgcn_cvt_pk_f32_fp8(u0, false), b0 = __builtin_amdgcn_cvt_pk_f32_fp8(u0, true);
        f32x2 a1 = __builtin_amdgcn_cvt_pk_f32_fp8(u1, false), b1 = __builtin_amdgcn_cvt_pk_f32_fp8(u1, true);
        f32x2 a2 = __builtin_amdgcn_cvt_pk_f32_fp8(u2, false), b2 = __builtin_amdgcn_cvt_pk_f32_fp8(u2, true);
        f32x2 a3 = __builtin_amdgcn_cvt_pk_f32_fp8(u3, false), b3 = __builtin_amdgcn_cvt_pk_f32_fp8(u3, true);
        f32x2 a4 = __builtin_amdgcn_cvt_pk_f32_fp8(u4, false), b4 = __builtin_amdgcn_cvt_pk_f32_fp8(u4, true);
        f32x2 a5 = __builtin_amdgcn_cvt_pk_f32_fp8(u5, false), b5 = __builtin_amdgcn_cvt_pk_f32_fp8(u5, true);
        f32x2 a6 = __builtin_amdgcn_cvt_pk_f32_fp8(u6, false), b6 = __builtin_amdgcn_cvt_pk_f32_fp8(u6, true);
        f32x2 a7 = __builtin_amdgcn_cvt_pk_f32_fp8(u7, false), b7 = __builtin_amdgcn_cvt_pk_f32_fp8(u7, true);
        f32x2 a8 = __builtin_amdgcn_cvt_pk_f32_fp8(u8, false), b8 = __builtin_amdgcn_cvt_pk_f32_fp8(u8, true);
        f32x2 a9 = __builtin_amdgcn_cvt_pk_f32_fp8(u9, false), b9 = __builtin_amdgcn_cvt_pk_f32_fp8(u9, true);
        f32x2 aa = __builtin_amdgcn_cvt_pk_f32_fp8(ua, false), ba = __builtin_amdgcn_cvt_pk_f32_fp8(ua, true);
        f32x2 ab = __builtin_amdgcn_cvt_pk_f32_fp8(ub, false), bb2 = __builtin_amdgcn_cvt_pk_f32_fp8(ub, true);
        f32x2 ac = __builtin_amdgcn_cvt_pk_f32_fp8(uc, false), bc = __builtin_amdgcn_cvt_pk_f32_fp8(uc, true);
        f32x2 ad = __builtin_amdgcn_cvt_pk_f32_fp8(ud, false), bd = __builtin_amdgcn_cvt_pk_f32_fp8(ud, true);
        f32x2 ae = __builtin_amdgcn_cvt_pk_f32_fp8(ue, false), be = __builtin_amdgcn_cvt_pk_f32_fp8(ue, true);
        f32x2 af2 = __builtin_amdgcn_cvt_pk_f32_fp8(uf, false), bf2 = __builtin_amdgcn_cvt_pk_f32_fp8(uf, true);
        acc.x += (((a0.x + a1.x) + (a2.x + a3.x)) + ((a4.x + a5.x) + (a6.x + a7.x)))
               + (((a8.x + a9.x) + (aa.x + ab.x)) + ((ac.x + ad.x) + (ae.x + af2.x)));
        acc.y += (((a0.y + a1.y) + (a2.y + a3.y)) + ((a4.y + a5.y) + (a6.y + a7.y)))
               + (((a8.y + a9.y) + (aa.y + ab.y)) + ((ac.y + ad.y) + (ae.y + af2.y)));
        acc.z += (((b0.x + b1.x) + (b2.x + b3.x)) + ((b4.x + b5.x) + (b6.x + b7.x)))
               + (((b8.x + b9.x) + (ba.x + bb2.x)) + ((bc.x + bd.x) + (be.x + bf2.x)));
        acc.w += (((b0.y + b1.y) + (b2.y + b3.y)) + ((b4.y + b5.y) + (b6.y + b7.y)))
               + (((b8.y + b9.y) + (ba.y + bb2.y)) + ((bc.y + bd.y) + (be.y + bf2.y)));
    }
    for (; p + 8 <= n; p += 8) {
        uint4 iv0 = *(const uint4*)(cs + p);
        unsigned int u0 = mrow[(size_t)(iv0.x & 0xffffu) * 64];
        unsigned int u1 = mrow[(size_t)(iv0.x >> 16)    * 64];
        unsigned int u2 = mrow[(size_t)(iv0.y & 0xffffu) * 64];
        unsigned int u3 = mrow[(size_t)(iv0.y >> 16)    * 64];
        unsigned int u4 = mrow[(size_t)(iv0.z & 0xffffu) * 64];
        unsigned int u5 = mrow[(size_t)(iv0.z >> 16)    * 64];
        unsigned int u6 = mrow[(size_t)(iv0.w & 0xffffu) * 64];
        unsigned int u7 = mrow[(size_t)(iv0.w >> 16)    * 64];
        f32x2 a0 = __builtin_amdgcn_cvt_pk_f32_fp8(u0, false), b0 = __builtin_amdgcn_cvt_pk_f32_fp8(u0, true);
        f32x2 a1 = __builtin_amdgcn_cvt_pk_f32_fp8(u1, false), b1 = __builtin_amdgcn_cvt_pk_f32_fp8(u1, true);
        f32x2 a2 = __builtin_amdgcn_cvt_pk_f32_fp8(u2, false), b2 = __builtin_amdgcn_cvt_pk_f32_fp8(u2, true);
        f32x2 a3 = __builtin_amdgcn_cvt_pk_f32_fp8(u3, false), b3 = __builtin_amdgcn_cvt_pk_f32_fp8(u3, true);
        f32x2 a4 = __builtin_amdgcn_cvt_pk_f32_fp8(u4, false), b4 = __builtin_amdgcn_cvt_pk_f32_fp8(u4, true);
        f32x2 a5 = __builtin_amdgcn_cvt_pk_f32_fp8(u5, false), b5 = __builtin_amdgcn_cvt_pk_f32_fp8(u5, true);
        f32x2 a6 = __builtin_amdgcn_cvt_pk_f32_fp8(u6, false), b6 = __builtin_amdgcn_cvt_pk_f32_fp8(u6, true);
        f32x2 a7 = __builtin_amdgcn_cvt_pk_f32_fp8(u7, false), b7 = __builtin_amdgcn_cvt_pk_f32_fp8(u7, true);
        acc.x += ((a0.x + a1.x) + (a2.x + a3.x)) + ((a4.x + a5.x) + (a6.x + a7.x));
        acc.y += ((a0.y + a1.y) + (a2.y + a3.y)) + ((a4.y + a5.y) + (a6.y + a7.y));
        acc.z += ((b0.x + b1.x) + (b2.x + b3.x)) + ((b4.x + b5.x) + (b6.x + b7.x));
        acc.w += ((b0.y + b1.y) + (b2.y + b3.y)) + ((b4.y + b5.y) + (b6.y + b7.y));
    }
    for (; p < n; ++p) {
        int s = cs[p];
        unsigned int u = mrow[(size_t)s * 64];
        f32x2 a = __builtin_amdgcn_cvt_pk_f32_fp8(u, false);
        f32x2 b = __builtin_amdgcn_cvt_pk_f32_fp8(u, true);
        acc.x += a.x; acc.y += a.y; acc.z += b.x; acc.w += b.y;
    }
    float di = dinv[node];
    const float4 bb = *(const float4*)(bias + lane * 4);
    acc.x = acc.x * di + bb.x; acc.y = acc.y * di + bb.y;
    acc.z = acc.z * di + bb.z; acc.w = acc.w * di + bb.w;
    if (do_relu) {
        acc.x = fmaxf(acc.x, 0.f); acc.y = fmaxf(acc.y, 0.f);
        acc.z = fmaxf(acc.z, 0.f); acc.w = fmaxf(acc.w, 0.f);
    }
    outb[(size_t)node * 64 + lane] = pk4fp8(acc.x, acc.y, acc.z, acc.w);
}

// ---------------- pooling stage A: one block per (graph, chunk), NO atomics ----------------
// batch sorted -> graph g owns contiguous rows [lb(g), ub(g)). Block (g,c) sums its slice
// branch-free (fixed g, independent loads pipeline), LDS-reduces 4 subwaves, writes a dense
// 1KB partial. Every (g,c) slot written -> no zeroing, no atomics, no ctr.
__global__ __launch_bounds__(256) void k_poolA(const unsigned int* __restrict__ h,  // [NN][64] dwords
                                               const int* __restrict__ batch,
                                               float* __restrict__ partial) {       // [PCH][GG*256]
    __shared__ float red[1024];      // [sub][fd*4+k]
    __shared__ int bnd[2];
    int g = blockIdx.x >> 6, c = blockIdx.x & (PCH - 1);
    int t = threadIdx.x, sub = t >> 6, fd = t & 63;
    if (t < 2) {
        int key = g + t;             // t=0: lower_bound(g); t=1: lower_bound(g+1)
        int lo = 0, hi = NN;
        while (lo < hi) { int mid = (lo + hi) >> 1; if (batch[mid] < key) lo = mid + 1; else hi = mid; }
        bnd[t] = lo;
    }
    __syncthreads();
    int start = bnd[0], len = bnd[1] - bnd[0];
    int r0 = start + (int)(((long long)len * c) >> 6);
    int r1 = start + (int)(((long long)len * (c + 1)) >> 6);
    float a0 = 0.f, a1 = 0.f, a2 = 0.f, a3 = 0.f;
    for (int i = r0 + sub; i < r1; i += 4) {
        unsigned int u = h[(size_t)i * 64 + fd];
        f32x2 lo = __builtin_amdgcn_cvt_pk_f32_fp8(u, false);
        f32x2 hi = __builtin_amdgcn_cvt_pk_f32_fp8(u, true);
        a0 += lo.x; a1 += lo.y; a2 += hi.x; a3 += hi.y;
    }
    red[sub * 256 + fd * 4 + 0] = a0;
    red[sub * 256 + fd * 4 + 1] = a1;
    red[sub * 256 + fd * 4 + 2] = a2;
    red[sub * 256 + fd * 4 + 3] = a3;
    __syncthreads();
    if (t < 64) {
        float4 s;
        s.x = (red[t * 4 + 0] + red[256 + t * 4 + 0]) + (red[512 + t * 4 + 0] + red[768 + t * 4 + 0]);
        s.y = (red[t * 4 + 1] + red[256 + t * 4 + 1]) + (red[512 + t * 4 + 1] + red[768 + t * 4 + 1]);
        s.z = (red[t * 4 + 2] + red[256 + t * 4 + 2]) + (red[512 + t * 4 + 2] + red[768 + t * 4 + 2]);
        s.w = (red[t * 4 + 3] + red[256 + t * 4 + 3]) + (red[512 + t * 4 + 3] + red[768 + t * 4 + 3]);
        *(float4*)(partial + (size_t)c * (GG * 256) + g * 256 + t * 4) = s;
    }
}

// ---------------- pooling stage B + head: one block per graph (out[g] independent) ----------------
__global__ __launch_bounds__(256) void k_poolB(const float* __restrict__ partial,   // [PCH][GG*256]
                                               const int* __restrict__ batch,
                                               const float* __restrict__ Wf, const float* __restrict__ bf,
                                               const float* __restrict__ Wp, const float* __restrict__ bp,
                                               float* __restrict__ out) {
    __shared__ float pg[256];
    __shared__ float zred[4][64];
    __shared__ float zs[64];
    __shared__ int bnd[2];
    int g = blockIdx.x, t = threadIdx.x;
    if (t < 2) {
        int key = g + t;
        int lo = 0, hi = NN;
        while (lo < hi) { int mid = (lo + hi) >> 1; if (batch[mid] < key) lo = mid + 1; else hi = mid; }
        bnd[t] = lo;
    }
    float s = 0.f;
    #pragma unroll 8
    for (int c = 0; c < PCH; ++c) s += partial[(size_t)c * (GG * 256) + g * 256 + t];
    pg[t] = s;
    __syncthreads();
    float inv = 1.f / fmaxf((float)(bnd[1] - bnd[0]), 1.f);
    int j = t & 63, part = t >> 6;
    float zp = 0.f;
    for (int k = part * 64; k < part * 64 + 64; ++k) zp += pg[k] * Wf[k * 64 + j];
    zred[part][j] = zp;
    __syncthreads();
    if (t < 64) {
        float z = ((zred[0][t] + zred[1][t]) + (zred[2][t] + zred[3][t])) * inv + bf[t];
        zs[t] = z * Wp[t];
    }
    __syncthreads();
    if (t == 0) {
        float o = 0.f;
        for (int j2 = 0; j2 < 64; ++j2) o += zs[j2];
        o += bp[0];
        out[g] = 1.f / (1.f + expf(-o));
    }
}

extern "C" void kernel_launch(void* const* d_in, const int* in_sizes, int n_in,
                              void* d_out, int out_size, void* d_ws, size_t ws_size,
                              hipStream_t stream) {
    const float* x   = (const float*)d_in[0];
    const int*   ei  = (const int*)d_in[1];
    const int*   bat = (const int*)d_in[2];
    const float* W1  = (const float*)d_in[3];
    const float* b1  = (const float*)d_in[4];
    const float* W2  = (const float*)d_in[5];
    const float* b2  = (const float*)d_in[6];
    const float* W3  = (const float*)d_in[7];
    const float* b3  = (const float*)d_in[8];
    const float* Wf  = (const float*)d_in[9];
    const float* bf  = (const float*)d_in[10];
    const float* Wp  = (const float*)d_in[11];
    const float* bp  = (const float*)d_in[12];
    float* out = (float*)d_out;

    char* w = (char*)d_ws;
    unsigned char* xb  = (unsigned char*)w;  w += (size_t)NN * DD;         // fp8 x, 25.6 MB
    unsigned char* mb  = (unsigned char*)w;  w += (size_t)NN * HH;         // fp8 prescaled gemm out
    unsigned char* hb  = (unsigned char*)w;  w += (size_t)NCH * 25000 * 4; // histg (12.8 used), then fp8 h
    unsigned char* hb2 = (unsigned char*)w;  w += (size_t)NCH * 25000 * 4; // offg, then fp8 h
    unsigned char* W1t = (unsigned char*)w;  w += (size_t)DD * HH;
    unsigned char* W2t = (unsigned char*)w;  w += (size_t)HH * HH;
    unsigned char* W3t = (unsigned char*)w;  w += (size_t)HH * HH;
    float* dinv   = (float*)w;               w += (size_t)NN * 4;
    int*   cnt    = (int*)w;                 w += (size_t)NN * 4;
    unsigned short* bucket = (unsigned short*)w; w += (size_t)NN * BK * 2; // 9.6 MB
    float* partial = (float*)w;              w += (size_t)PCH * GG * HH * 4; // 1 MB dense partials

    unsigned int* histg = (unsigned int*)hb;
    unsigned int* offg  = (unsigned int*)hb2;

    // build: fused u8-hist + converts | scan | place   (no memset needed anywhere)
    k_hist_cvt<<<7786, 256, 0, stream>>>(ei, histg, x, xb, W1, W2, W3, W1t, W2t, W3t);
    k_scan<<<391, 256, 0, stream>>>(histg, offg, cnt, dinv);
    k_place<<<2048, 256, 0, stream>>>(ei, offg, bucket);

    dim3 gg((NN + 127) / 128, 2);
    // layer 1
    k_gemm_fp8<<<gg, 256, 0, stream>>>(xb, W1t, dinv, mb, NN, DD);
    k_agg<<<(NN + 3) / 4, 256, 0, stream>>>((const unsigned int*)mb, b1, dinv, cnt, bucket,
                                            (unsigned int*)hb, 1);
    // layer 2
    k_gemm_fp8<<<gg, 256, 0, stream>>>(hb, W2t, dinv, mb, NN, HH);
    k_agg<<<(NN + 3) / 4, 256, 0, stream>>>((const unsigned int*)mb, b2, dinv, cnt, bucket,
                                            (unsigned int*)hb2, 1);
    // layer 3
    k_gemm_fp8<<<gg, 256, 0, stream>>>(hb2, W3t, dinv, mb, NN, HH);
    k_agg<<<(NN + 3) / 4, 256, 0, stream>>>((const unsigned int*)mb, b3, dinv, cnt, bucket,
                                            (unsigned int*)hb, 0);

    // pooling: atomic-free 2-stage (A: 16x64 blocks dense partials; B: 16 independent graph heads)
    k_poolA<<<GG * PCH, 256, 0, stream>>>((const unsigned int*)hb, bat, partial);
    k_poolB<<<GG, 256, 0, stream>>>(partial, bat, Wf, bf, Wp, bp, out);
}